// Round 8
// baseline (240.802 us; speedup 1.0000x reference)
//
#include <hip/hip_runtime.h>
#include <cstddef>
#include <cstdint>

namespace {
constexpr int kB   = 8;
constexpr int kT   = 2048;   // Tv == Ta
constexpr int kD   = 256;
constexpr int kK   = 8;      // num_neighbors (fixed by problem)
constexpr int kM   = kB * kT;
constexpr int kNC  = kB * kT;     // 16384 columns (b,s)
constexpr int kColCap = 64;       // bucket slots per column (mean load ~0.55)
constexpr int kOvCap  = 1 << 17;  // overflow list (normally empty)
constexpr int kStr = 264;         // padded LDS stride (gemm X tile only)
constexpr float kMinNormalF = 1.17549435e-38f;  // 2^-126: fp32 exp flush boundary
}

typedef __attribute__((ext_vector_type(8)))  __bf16 bf16x8;
typedef __attribute__((ext_vector_type(16))) float  f32x16;

__device__ inline unsigned short f2bf_rne(float x) {
  unsigned u = __float_as_uint(x);
  unsigned r = (u + 0x7FFFu + ((u >> 16) & 1u)) >> 16;
  return (unsigned short)r;
}
__device__ inline float bf2f(unsigned short h) {
  return __uint_as_float((unsigned)h << 16);
}
union FragU { uint4 u4; bf16x8 v; };

// Async global->LDS, 16B per lane (m97's width=16 path). LDS dest is
// wave-uniform base + lane*16; global addr is per-lane.
__device__ inline void async16(const unsigned short* g, unsigned short* l) {
  __builtin_amdgcn_global_load_lds(
      (const __attribute__((address_space(1))) unsigned int*)(const void*)g,
      (__attribute__((address_space(3))) unsigned int*)(void*)l, 16, 0, 0);
}

// Stage a 64-row x 256-short tile (row stride kD) into S via global_load_lds.
// XOR swizzle: 16B-block at physical (row, c ^ (row&31)) holds logical block c.
// Global side stays inside each 512B row (perfectly coalesced); read side
// (lanes = distinct rows) hits 32 distinct 16B blocks = conflict-free.
__device__ inline void stage_tile_async(const unsigned short* src,
                                        unsigned short* S, int w, int lane) {
  const int hi = lane >> 5, lo = lane & 31;
#pragma unroll
  for (int i = 0; i < 8; ++i) {
    const int p = w * 8 + i;
    const int rowl = p * 2 + hi;
    const int c = lo ^ (rowl & 31);
    async16(src + (size_t)rowl * kD + c * 8, S + p * 512);
  }
}
// Read one 16B MFMA fragment (logical shorts [kc*16+half*8 ..)) from the
// swizzled tile.
__device__ inline uint4 lds_frag(const unsigned short* S, int row, int kc, int half) {
  const int c = (kc * 2 + half) ^ (row & 31);
  return *reinterpret_cast<const uint4*>(S + row * 256 + c * 8);
}

// ---- Kernel 0: prep = weight transpose (blocks 0..127) + zero scratch/out --
// Zero set = [vn2|an2|colCount|ovCount|flags] (contiguous) + out.
// R7 LESSON: vn2/an2 MUST be zeroed — gemm's row norm has TWO contributors
// per row (wc=0 and wc=1 waves, one per 32-col half); plain store raced and
// kept half the norm -> absmax 3.8 selection corruption. atomicAdd restored.
__global__ __launch_bounds__(256) void prep(const float* __restrict__ W0,
                                            const float* __restrict__ W1,
                                            unsigned short* __restrict__ T0,
                                            unsigned short* __restrict__ T1,
                                            unsigned* __restrict__ zeroBase,
                                            int zeroWords,
                                            unsigned* __restrict__ outW) {
  const int blk = blockIdx.x;
  if (blk < 128) {
    const float* W = (blk & 64) ? W1 : W0;
    unsigned short* WT = (blk & 64) ? T1 : T0;
    const int t = blk & 63;
    const int c0 = (t & 7) * 32, k0 = (t >> 3) * 32;
    __shared__ float tile[32][33];
    const int tx = threadIdx.x & 31, ty = threadIdx.x >> 5;
#pragma unroll
    for (int i = 0; i < 4; ++i)
      tile[ty + i * 8][tx] = W[(size_t)(k0 + ty + i * 8) * kD + c0 + tx];
    __syncthreads();
#pragma unroll
    for (int i = 0; i < 4; ++i)
      WT[(size_t)(c0 + ty + i * 8) * kD + k0 + tx] = f2bf_rne(tile[tx][ty + i * 8]);
  } else {
    for (int i = (blk - 128) * 256 + threadIdx.x; i < zeroWords; i += 32 * 256)
      zeroBase[i] = 0u;
    // zero the output (finwsum accumulates into it atomically)
    for (int i = (blk - 128) * 256 + threadIdx.x; i < 2 * kB * kK * kD; i += 32 * 256)
      outW[i] = 0u;
  }
}

// ---- Kernel 1: Cb = bf16( bf16(X) @ WT^T ) + fused row norms ---------------
// Single X pass + 2-phase WT prefetch (R2 known-good, atomicAdd norms).
__global__ __launch_bounds__(256) void gemm_hyb(const float* __restrict__ Xv,
                                                const float* __restrict__ Xa,
                                                const unsigned short* __restrict__ WvT,
                                                const unsigned short* __restrict__ WaT,
                                                unsigned short* __restrict__ Cv,
                                                unsigned short* __restrict__ Ca,
                                                float* __restrict__ nv,
                                                float* __restrict__ na) {
  __shared__ unsigned short S[64 * kStr + 64 * 256];  // 65.0 KB
  unsigned short* bufA = S;            // X (kStr stride), later WT buffer
  unsigned short* bufB = S + 64 * kStr;
  const int z = blockIdx.z;
  const float* X = z ? Xa : Xv;
  const unsigned short* WT = z ? WaT : WvT;
  unsigned short* Cb = z ? Ca : Cv;
  float* nrm = z ? na : nv;
  const int r0 = blockIdx.x * 64;
  const int tid = threadIdx.x;
  const int w = tid >> 6, lane = tid & 63;
  const int wt = w & 1, wc = w >> 1;
  const int half = lane >> 5, ln = lane & 31;

  // stage X: 64 rows x 256 fp32, coalesced, cast inline (padded layout)
#pragma unroll
  for (int i = 0; i < 16; ++i) {
    const int idx = i * 256 + tid;
    const int row = idx >> 6, g = idx & 63;
    const float4 v = *reinterpret_cast<const float4*>(X + (size_t)(r0 + row) * kD + g * 4);
    ushort4 o;
    o.x = f2bf_rne(v.x); o.y = f2bf_rne(v.y); o.z = f2bf_rne(v.z); o.w = f2bf_rne(v.w);
    *reinterpret_cast<ushort4*>(bufA + row * kStr + g * 4) = o;
  }
  __syncthreads();

  // prefetch WT tile 0 into bufB (disjoint from X region), then read afr
  stage_tile_async(WT, bufB, w, lane);
  uint4 afr[16];
#pragma unroll
  for (int kc = 0; kc < 16; ++kc)
    afr[kc] = *reinterpret_cast<const uint4*>(bufA + (wt * 32 + ln) * kStr + kc * 16 + half * 8);
  __syncthreads();  // afr reads done block-wide; WT0 resident (vmcnt drained)

  float ns[16];
#pragma unroll
  for (int r = 0; r < 16; ++r) ns[r] = 0.0f;

  for (int ct = 0; ct < 4; ++ct) {
    unsigned short* cur = (ct & 1) ? bufA : bufB;
    unsigned short* nxt = (ct & 1) ? bufB : bufA;
    if (ct < 3)
      stage_tile_async(WT + (size_t)(ct + 1) * 64 * kD, nxt, w, lane);
    const int c0 = ct * 64;
    f32x16 acc;
#pragma unroll
    for (int i = 0; i < 16; ++i) acc[i] = 0.0f;
#pragma unroll
    for (int kc = 0; kc < 16; ++kc) {
      FragU fa, fb;
      fa.u4 = afr[kc];
      fb.u4 = lds_frag(cur, wc * 32 + ln, kc, half);
      acc = __builtin_amdgcn_mfma_f32_32x32x16_bf16(fa.v, fb.v, acc, 0, 0, 0);
    }
    const int col = c0 + wc * 32 + ln;
#pragma unroll
    for (int r = 0; r < 16; ++r) {
      const int row = r0 + wt * 32 + (r & 3) + 8 * (r >> 2) + 4 * half;
      const unsigned short us = f2bf_rne(acc[r]);
      Cb[(size_t)row * kD + col] = us;
      const float f = bf2f(us);
      ns[r] += f * f;
    }
    if (ct < 3) __syncthreads();  // next tile resident; cur reads done
  }
#pragma unroll
  for (int r = 0; r < 16; ++r) {
    float v = ns[r];
#pragma unroll
    for (int off = 1; off < 32; off <<= 1) v += __shfl_xor(v, off, 64);
    if (ln == 0) {
      const int row = r0 + wt * 32 + (r & 3) + 8 * (r >> 2) + 4 * half;
      atomicAdd(nrm + row, v);   // TWO contributors per row (wc=0,1)
    }
  }
}

// ---- Kernel 2: distance keys, 128t x 512s ----------------------------------
// v18 = v15's exact staging/compute structure with DOUBLE the s-span per
// block: 8 stages instead of 4 -> 512 blocks (still 2/CU, LDS-bound), half
// the prologue barriers, half the duplicate vm staging. MFMA ops, operand
// bits and epilogue arithmetic identical -> selection bit-identical.
// DO NOT restructure staging/VGPR: R3 (launch_bounds 4) and R4 (LDS-free)
// both spilled (53-65 MB scratch WRITE_SIZE, 1.2-1.7x total regressions).
__global__ __launch_bounds__(256) void keys_v18(const unsigned short* __restrict__ vmb,
                                                const unsigned short* __restrict__ amb,
                                                const float* __restrict__ vn2,
                                                const float* __restrict__ an2,
                                                unsigned* __restrict__ colCount,
                                                uint2* __restrict__ colRecs,
                                                unsigned* __restrict__ ovCount,
                                                uint2* __restrict__ ovRecs) {
  __shared__ unsigned short S[2][64 * 256];   // 2 x 32KB, swizzled tiles
  // grid (16,4,8) = 512 blocks; flatten x-fastest, remap so XCD k
  // (dispatch id % 8) runs exactly batch b=k (64 blocks). 512 % 8 == 0.
  const int hw = blockIdx.x + (blockIdx.y << 4) + (blockIdx.z << 6);
  const int lg = ((hw & 7) << 6) | (hw >> 3);
  const int b = lg >> 6;
  const int t0 = (lg & 15) << 7;          // *128
  const int sr0 = ((lg >> 4) & 3) << 9;   // *512
  const int tid = threadIdx.x;
  const int w = tid >> 6, lane = tid & 63;
  const int half = lane >> 5, ln = lane & 31;

  // A: both 64-row vm halves staged concurrently; wave w reads half (w>>1)
  stage_tile_async(vmb + ((size_t)b * kT + t0) * kD, S[0], w, lane);
  stage_tile_async(vmb + ((size_t)b * kT + t0 + 64) * kD, S[1], w, lane);
  __syncthreads();  // both halves resident
  uint4 afr[16];
  {
    const unsigned short* Sa = S[w >> 1];
#pragma unroll
    for (int kc = 0; kc < 16; ++kc)
      afr[kc] = lds_frag(Sa, (w & 1) * 32 + ln, kc, half);
  }
  __syncthreads();  // afr reads done block-wide before buffers are reused

  // prologue: stage am tile 0
  stage_tile_async(amb + ((size_t)b * kT + sr0) * kD, S[0], w, lane);
  __syncthreads();  // tile 0 resident

  const float* v2p = vn2 + (size_t)b * kT + t0 + w * 32;

  for (int st = 0; st < 8; ++st) {
    const int s0 = sr0 + st * 64;
    const int cur = st & 1;
    if (st < 7)  // prefetch next tile; latency hides under MFMA + epilogue
      stage_tile_async(amb + ((size_t)b * kT + s0 + 64) * kD, S[cur ^ 1], w, lane);
    f32x16 acc[2];
#pragma unroll
    for (int j = 0; j < 2; ++j)
#pragma unroll
      for (int i = 0; i < 16; ++i) acc[j][i] = 0.0f;
#pragma unroll
    for (int kc = 0; kc < 16; ++kc) {
      FragU fa; fa.u4 = afr[kc];
#pragma unroll
      for (int ss = 0; ss < 2; ++ss) {
        FragU fb;
        fb.u4 = lds_frag(S[cur], ss * 32 + ln, kc, half);
        acc[ss] = __builtin_amdgcn_mfma_f32_32x32x16_bf16(fa.v, fb.v, acc[ss], 0, 0, 0);
      }
    }
    // epilogue: col(s)=lane&31, row(t)=(reg&3)+8*(reg>>2)+4*half
    float a2s[2];
#pragma unroll
    for (int ss = 0; ss < 2; ++ss)
      a2s[ss] = an2[(size_t)b * kT + s0 + ss * 32 + ln];
#pragma unroll
    for (int g = 0; g < 4; ++g) {
      const float4 v2 = *reinterpret_cast<const float4*>(v2p + g * 8 + half * 4);
      const float v2a[4] = {v2.x, v2.y, v2.z, v2.w};
#pragma unroll
      for (int ss = 0; ss < 2; ++ss) {
        const int s = s0 + ss * 32 + ln;
        const float a2 = a2s[ss];
        const int c = (b << 11) | s;
#pragma unroll
        for (int q = 0; q < 4; ++q) {
          const float raw = v2a[q] + a2 - 2.0f * acc[ss][4 * g + q];
          if (raw < 7744.0f) {  // == dist < 88; ~3e-4 of entries
            const float dist = sqrtf(fmaxf(raw, 0.0f));
            const float e = expf(-dist);
            if (e >= kMinNormalF) {
              const int t = t0 + w * 32 + g * 8 + half * 4 + q;
              const unsigned slot = atomicAdd(&colCount[c], 1u);
              if (slot < (unsigned)kColCap) {
                colRecs[(size_t)c * kColCap + slot] = make_uint2(__float_as_uint(e), (unsigned)t);
              } else {
                const unsigned pos = ((unsigned)b << 22) | ((unsigned)s << 11) | (unsigned)t;
                const unsigned oi = atomicAdd(ovCount, 1u);
                if (oi < (unsigned)kOvCap) ovRecs[oi] = make_uint2(__float_as_uint(e), pos);
              }
            }
          }
        }
      }
    }
    if (st < 7) __syncthreads();  // next tile resident; S[cur] reads done
  }
}

// ---- Kernel 3: merged finalize + weighted sum (one dispatch) ---------------
// Blocks 0..7: per-batch finalize (LDS-privatized hist, identical selection
// logic), agent-scope hist stores, __threadfence, release flag[b].
// Blocks 8..263: wsum. Each PRE-WARMS its 128 KB X slice into L2 (hides the
// finalize latency), spins on flag[b] (thread 0 + s_sleep), reads hist with
// agent-scope atomic loads (per-XCD L2s are not coherent - G16), then
// accumulates out[b,j,:] = (1/Ta) sum_t hist[b,t,j]*X[b,t,:].
// 264 blocks @ 64 KB LDS = 2/CU -> all co-resident under any dispatch order
// (264 < 512 slots): deadlock-free. Finalize blocks never wait on anyone.
__global__ __launch_bounds__(256) void finwsum(const unsigned* __restrict__ colCount,
                                               const uint2* __restrict__ colRecs,
                                               const unsigned* __restrict__ ovCount,
                                               const uint2* __restrict__ ovRecs,
                                               unsigned* __restrict__ hist,
                                               unsigned* __restrict__ flags,
                                               const float* __restrict__ visual,
                                               const float* __restrict__ audio,
                                               float* __restrict__ out) {
  __shared__ unsigned lhist[kT * kK];   // 64 KB (fin); wsum uses first 2 KB
  const int tid = threadIdx.x;
  if (blockIdx.x < 8) {
    // ---------------- finalize part ----------------
    const int b = blockIdx.x;
    for (int i = tid; i < kT * kK; i += 256) lhist[i] = 0u;
    __syncthreads();
    for (int s = tid; s < kT; s += 256) {
      const int c = (b << 11) | s;
      unsigned K[8]; int T[8];
#pragma unroll
      for (int i = 0; i < 8; ++i) { K[i] = 0u; T[i] = 0x7FFFFFFF; }
      const int cnt = (int)colCount[c];
      const int m = min(cnt, kColCap);
      for (int i = 0; i < m; ++i) {
        const uint2 r = colRecs[(size_t)c * kColCap + i];
        const unsigned kx = r.x; const int tx = (int)r.y;
        if (kx > K[7] || (kx == K[7] && tx < T[7])) {
          K[7] = kx; T[7] = tx;
#pragma unroll
          for (int q = 7; q >= 1; --q) {
            const bool sw = (K[q] > K[q - 1]) || (K[q] == K[q - 1] && T[q] < T[q - 1]);
            if (sw) {
              const unsigned tk = K[q]; K[q] = K[q - 1]; K[q - 1] = tk;
              const int tt = T[q];      T[q] = T[q - 1]; T[q - 1] = tt;
            }
          }
        }
      }
      if (cnt > kColCap) {  // correctness fallback; normally never taken
        int n = (int)*ovCount;
        if (n > kOvCap) n = kOvCap;
        for (int i = 0; i < n; ++i) {
          const uint2 r = ovRecs[i];
          if ((int)(r.y >> 11) == c) {
            const unsigned kx = r.x; const int tx = (int)(r.y & 2047u);
            if (kx > K[7] || (kx == K[7] && tx < T[7])) {
              K[7] = kx; T[7] = tx;
#pragma unroll
              for (int q = 7; q >= 1; --q) {
                const bool sw = (K[q] > K[q - 1]) || (K[q] == K[q - 1] && T[q] < T[q - 1]);
                if (sw) {
                  const unsigned tk = K[q]; K[q] = K[q - 1]; K[q - 1] = tk;
                  const int tt = T[q];      T[q] = T[q - 1]; T[q - 1] = tt;
                }
              }
            }
          }
        }
      }
      int mcnt = 0;
#pragma unroll
      for (int i = 0; i < 8; ++i) if (K[i] > 0u) mcnt++;
      int outv[8];
#pragma unroll
      for (int i = 0; i < 8; ++i) outv[i] = T[i];
      int cand = 0;
      for (int r = mcnt; r < 8; ++r) {
        bool taken = true;
        while (taken) {
          taken = false;
#pragma unroll
          for (int q = 0; q < 8; ++q)
            if (q < mcnt && T[q] == cand) taken = true;
          if (taken) cand++;
        }
        outv[r] = cand++;
      }
#pragma unroll
      for (int j = 0; j < 8; ++j)
        atomicAdd(&lhist[(outv[j] << 3) + j], 1u);
    }
    __syncthreads();
    // agent-scope stores so cross-XCD readers see fresh values
    unsigned* hb = hist + ((size_t)b << 11) * kK;
    for (int i = tid; i < kT * kK; i += 256)
      __hip_atomic_store(&hb[i], lhist[i], __ATOMIC_RELAXED, __HIP_MEMORY_SCOPE_AGENT);
    __threadfence();
    __syncthreads();
    if (tid == 0)
      __hip_atomic_store(&flags[b], 1u, __ATOMIC_RELEASE, __HIP_MEMORY_SCOPE_AGENT);
  } else {
    // ---------------- wsum part ----------------
    const int u = (int)blockIdx.x - 8;     // 0..255 = 8 b x 32 t-tiles
    const int b = u >> 5;
    const int t0 = (u & 31) * 64;
    const int d = tid;
    const size_t xbase = ((size_t)b * kT + t0) * kD + d;
    // pre-warm this block's X slice into L2 while finalize runs
    float warm = 0.f;
    for (int i = 0; i < 64; ++i)
      warm += visual[xbase + (size_t)i * kD] + audio[xbase + (size_t)i * kD];
    asm volatile("" :: "v"(warm));   // keep the prefetch alive (no DCE)
    if (tid == 0) {
      while (__hip_atomic_load(&flags[b], __ATOMIC_ACQUIRE,
                               __HIP_MEMORY_SCOPE_AGENT) == 0u)
        __builtin_amdgcn_s_sleep(8);
    }
    __syncthreads();
    const unsigned* hsrc = hist + (((size_t)b << 11) + t0) * kK;
    lhist[d] = __hip_atomic_load(&hsrc[d], __ATOMIC_RELAXED, __HIP_MEMORY_SCOPE_AGENT);
    lhist[d + 256] = __hip_atomic_load(&hsrc[d + 256], __ATOMIC_RELAXED, __HIP_MEMORY_SCOPE_AGENT);
    __syncthreads();
    float accV[8], accA[8];
#pragma unroll
    for (int j = 0; j < 8; ++j) { accV[j] = 0.f; accA[j] = 0.f; }
    for (int i = 0; i < 64; ++i) {
      const float v = visual[xbase + (size_t)i * kD];
      const float a = audio[xbase + (size_t)i * kD];
#pragma unroll
      for (int j = 0; j < 8; ++j) {
        const float cf = (float)lhist[i * kK + j];
        accV[j] += cf * v;
        accA[j] += cf * a;
      }
    }
#pragma unroll
    for (int j = 0; j < 8; ++j) {
      const size_t bj = (size_t)b * kK + j;
      atomicAdd(&out[bj * kD + d], accV[j] * (1.0f / kT));
      atomicAdd(&out[(size_t)kB * kK * kD + bj * kD + d], accA[j] * (1.0f / kT));
    }
  }
}

extern "C" void kernel_launch(void* const* d_in, const int* in_sizes, int n_in,
                              void* d_out, int out_size, void* d_ws, size_t ws_size,
                              hipStream_t stream) {
  (void)in_sizes; (void)n_in; (void)out_size; (void)ws_size;
  const float* visual = (const float*)d_in[0];
  const float* audio  = (const float*)d_in[1];
  const float* Wv     = (const float*)d_in[2];
  const float* Wa     = (const float*)d_in[3];
  float* out = (float*)d_out;

  // workspace layout (~27 MB). [vn2|an2|colCount|ovCount|flags] contiguous,
  // zeroed by prep. hist fully rewritten by finwsum each run.
  char* ws = (char*)d_ws;
  unsigned short* WvT = (unsigned short*)ws;                // kD*kD bf16 128KB
  unsigned short* WaT = WvT + (size_t)kD * kD;
  unsigned short* vmb = WaT + (size_t)kD * kD;              // kM*kD bf16  8MB
  unsigned short* amb = vmb + (size_t)kM * kD;              // 8MB
  float* vn2 = (float*)(amb + (size_t)kM * kD);             // kM f32 (zeroed)
  float* an2 = vn2 + kM;                                    // kM f32 (zeroed)
  unsigned* colCount = (unsigned*)(an2 + kM);               // kNC u32 (zeroed)
  unsigned* ovCount  = colCount + kNC;                      // 1 u32 +7 pad (zeroed)
  unsigned* flags    = ovCount + 8;                         // kB u32 (zeroed)
  unsigned* hist     = flags + 8;                           // kM*kK u32 512KB
  uint2* colRecs = (uint2*)(hist + (size_t)kM * kK);        // kNC*kColCap uint2 8MB
  uint2* ovRecs  = colRecs + (size_t)kNC * kColCap;         // kOvCap uint2 1MB
  const int zeroWords = 2 * kM + kNC + 16;

  prep<<<dim3(160), 256, 0, stream>>>(Wv, Wa, WvT, WaT, (unsigned*)vn2, zeroWords,
                                      (unsigned*)out);
  gemm_hyb<<<dim3(kM / 64, 1, 2), 256, 0, stream>>>(visual, audio, WvT, WaT,
                                                    vmb, amb, vn2, an2);
  keys_v18<<<dim3(kT / 128, kT / 512, kB), 256, 0, stream>>>(vmb, amb, vn2, an2,
                                                             colCount, colRecs, ovCount, ovRecs);
  finwsum<<<dim3(8 + 256), 256, 0, stream>>>(colCount, colRecs, ovCount, ovRecs,
                                             hist, flags, visual, audio, out);
}

// Round 9
// 149.107 us; speedup vs baseline: 1.6150x; 1.6150x over previous
//
#include <hip/hip_runtime.h>
#include <cstddef>
#include <cstdint>

namespace {
constexpr int kB   = 8;
constexpr int kT   = 2048;   // Tv == Ta
constexpr int kD   = 256;
constexpr int kK   = 8;      // num_neighbors (fixed by problem)
constexpr int kM   = kB * kT;
constexpr int kNC  = kB * kT;     // 16384 columns (b,s)
constexpr int kColCap = 64;       // bucket slots per column (mean load ~0.55)
constexpr int kOvCap  = 1 << 17;  // overflow list (normally empty)
constexpr int kStr = 264;         // padded LDS stride (gemm X tile only)
constexpr float kMinNormalF = 1.17549435e-38f;  // 2^-126: fp32 exp flush boundary
}

typedef __attribute__((ext_vector_type(8)))  __bf16 bf16x8;
typedef __attribute__((ext_vector_type(16))) float  f32x16;

__device__ inline unsigned short f2bf_rne(float x) {
  unsigned u = __float_as_uint(x);
  unsigned r = (u + 0x7FFFu + ((u >> 16) & 1u)) >> 16;
  return (unsigned short)r;
}
__device__ inline float bf2f(unsigned short h) {
  return __uint_as_float((unsigned)h << 16);
}
union FragU { uint4 u4; bf16x8 v; };

// Async global->LDS, 16B per lane (m97's width=16 path). LDS dest is
// wave-uniform base + lane*16; global addr is per-lane.
__device__ inline void async16(const unsigned short* g, unsigned short* l) {
  __builtin_amdgcn_global_load_lds(
      (const __attribute__((address_space(1))) unsigned int*)(const void*)g,
      (__attribute__((address_space(3))) unsigned int*)(void*)l, 16, 0, 0);
}

// Stage a 64-row x 256-short tile (row stride kD) into S via global_load_lds.
// XOR swizzle: 16B-block at physical (row, c ^ (row&31)) holds logical block c.
// Global side stays inside each 512B row (perfectly coalesced); read side
// (lanes = distinct rows) hits 32 distinct 16B blocks = conflict-free.
__device__ inline void stage_tile_async(const unsigned short* src,
                                        unsigned short* S, int w, int lane) {
  const int hi = lane >> 5, lo = lane & 31;
#pragma unroll
  for (int i = 0; i < 8; ++i) {
    const int p = w * 8 + i;
    const int rowl = p * 2 + hi;
    const int c = lo ^ (rowl & 31);
    async16(src + (size_t)rowl * kD + c * 8, S + p * 512);
  }
}
// Read one 16B MFMA fragment (logical shorts [kc*16+half*8 ..)) from the
// swizzled tile.
__device__ inline uint4 lds_frag(const unsigned short* S, int row, int kc, int half) {
  const int c = (kc * 2 + half) ^ (row & 31);
  return *reinterpret_cast<const uint4*>(S + row * 256 + c * 8);
}

// ---- Kernel 0: prep = weight transpose (blocks 0..127) + zero scratch/out --
__global__ __launch_bounds__(256) void prep(const float* __restrict__ W0,
                                            const float* __restrict__ W1,
                                            unsigned short* __restrict__ T0,
                                            unsigned short* __restrict__ T1,
                                            unsigned* __restrict__ zeroBase,
                                            int zeroWords,
                                            unsigned* __restrict__ outW) {
  const int blk = blockIdx.x;
  if (blk < 128) {
    const float* W = (blk & 64) ? W1 : W0;
    unsigned short* WT = (blk & 64) ? T1 : T0;
    const int t = blk & 63;
    const int c0 = (t & 7) * 32, k0 = (t >> 3) * 32;
    __shared__ float tile[32][33];
    const int tx = threadIdx.x & 31, ty = threadIdx.x >> 5;
#pragma unroll
    for (int i = 0; i < 4; ++i)
      tile[ty + i * 8][tx] = W[(size_t)(k0 + ty + i * 8) * kD + c0 + tx];
    __syncthreads();
#pragma unroll
    for (int i = 0; i < 4; ++i)
      WT[(size_t)(c0 + ty + i * 8) * kD + k0 + tx] = f2bf_rne(tile[tx][ty + i * 8]);
  } else {
    for (int i = (blk - 128) * 256 + threadIdx.x; i < zeroWords; i += 32 * 256)
      zeroBase[i] = 0u;
    // zero the output (gather_fused accumulates into it atomically)
    for (int i = (blk - 128) * 256 + threadIdx.x; i < 2 * kB * kK * kD; i += 32 * 256)
      outW[i] = 0u;
  }
}

// ---- Kernel 1: Cb = bf16( bf16(X) @ WT^T ) + fused row norms ---------------
// Single X pass + 2-phase WT prefetch (R2 known-good, untouched).
// R7 LESSON: the row norm has TWO contributors per row (wc=0,1 waves, one per
// 32-col half) -> MUST be atomicAdd onto zeroed vn2/an2; a plain store races.
__global__ __launch_bounds__(256) void gemm_hyb(const float* __restrict__ Xv,
                                                const float* __restrict__ Xa,
                                                const unsigned short* __restrict__ WvT,
                                                const unsigned short* __restrict__ WaT,
                                                unsigned short* __restrict__ Cv,
                                                unsigned short* __restrict__ Ca,
                                                float* __restrict__ nv,
                                                float* __restrict__ na) {
  __shared__ unsigned short S[64 * kStr + 64 * 256];  // 65.0 KB
  unsigned short* bufA = S;            // X (kStr stride), later WT buffer
  unsigned short* bufB = S + 64 * kStr;
  const int z = blockIdx.z;
  const float* X = z ? Xa : Xv;
  const unsigned short* WT = z ? WaT : WvT;
  unsigned short* Cb = z ? Ca : Cv;
  float* nrm = z ? na : nv;
  const int r0 = blockIdx.x * 64;
  const int tid = threadIdx.x;
  const int w = tid >> 6, lane = tid & 63;
  const int wt = w & 1, wc = w >> 1;
  const int half = lane >> 5, ln = lane & 31;

  // stage X: 64 rows x 256 fp32, coalesced, cast inline (padded layout)
#pragma unroll
  for (int i = 0; i < 16; ++i) {
    const int idx = i * 256 + tid;
    const int row = idx >> 6, g = idx & 63;
    const float4 v = *reinterpret_cast<const float4*>(X + (size_t)(r0 + row) * kD + g * 4);
    ushort4 o;
    o.x = f2bf_rne(v.x); o.y = f2bf_rne(v.y); o.z = f2bf_rne(v.z); o.w = f2bf_rne(v.w);
    *reinterpret_cast<ushort4*>(bufA + row * kStr + g * 4) = o;
  }
  __syncthreads();

  // prefetch WT tile 0 into bufB (disjoint from X region), then read afr
  stage_tile_async(WT, bufB, w, lane);
  uint4 afr[16];
#pragma unroll
  for (int kc = 0; kc < 16; ++kc)
    afr[kc] = *reinterpret_cast<const uint4*>(bufA + (wt * 32 + ln) * kStr + kc * 16 + half * 8);
  __syncthreads();  // afr reads done block-wide; WT0 resident (vmcnt drained)

  float ns[16];
#pragma unroll
  for (int r = 0; r < 16; ++r) ns[r] = 0.0f;

  for (int ct = 0; ct < 4; ++ct) {
    unsigned short* cur = (ct & 1) ? bufA : bufB;
    unsigned short* nxt = (ct & 1) ? bufB : bufA;
    if (ct < 3)
      stage_tile_async(WT + (size_t)(ct + 1) * 64 * kD, nxt, w, lane);
    const int c0 = ct * 64;
    f32x16 acc;
#pragma unroll
    for (int i = 0; i < 16; ++i) acc[i] = 0.0f;
#pragma unroll
    for (int kc = 0; kc < 16; ++kc) {
      FragU fa, fb;
      fa.u4 = afr[kc];
      fb.u4 = lds_frag(cur, wc * 32 + ln, kc, half);
      acc = __builtin_amdgcn_mfma_f32_32x32x16_bf16(fa.v, fb.v, acc, 0, 0, 0);
    }
    const int col = c0 + wc * 32 + ln;
#pragma unroll
    for (int r = 0; r < 16; ++r) {
      const int row = r0 + wt * 32 + (r & 3) + 8 * (r >> 2) + 4 * half;
      const unsigned short us = f2bf_rne(acc[r]);
      Cb[(size_t)row * kD + col] = us;
      const float f = bf2f(us);
      ns[r] += f * f;
    }
    if (ct < 3) __syncthreads();  // next tile resident; cur reads done
  }
#pragma unroll
  for (int r = 0; r < 16; ++r) {
    float v = ns[r];
#pragma unroll
    for (int off = 1; off < 32; off <<= 1) v += __shfl_xor(v, off, 64);
    if (ln == 0) {
      const int row = r0 + wt * 32 + (r & 3) + 8 * (r >> 2) + 4 * half;
      atomicAdd(nrm + row, v);   // TWO contributors per row (wc=0,1)
    }
  }
}

// ---- Kernel 2: distance keys, 128t x 512s (keys_v18, HW-validated in R8) ---
// v15's exact staging/compute structure with double s-span per block: 8
// stages -> 512 blocks (still 2/CU), half the prologue barriers, half the
// duplicate vm staging. XCD remap bijective (b = hw&7 -> batch b on XCD b).
// MFMA ops, operand bits and epilogue arithmetic identical -> selection
// bit-identical (R8 passed at absmax 0.015625 with this exact kernel).
// DO NOT restructure staging/VGPR: R3 (launch_bounds 4) and R4 (LDS-free)
// both spilled (53-65 MB scratch WRITE_SIZE, 1.2-1.7x total regressions).
// DO NOT fuse with consumers: R8's producer-consumer handshake serialized
// the whole dispatch (127 us at 2-4% utilization).
__global__ __launch_bounds__(256) void keys_v18(const unsigned short* __restrict__ vmb,
                                                const unsigned short* __restrict__ amb,
                                                const float* __restrict__ vn2,
                                                const float* __restrict__ an2,
                                                unsigned* __restrict__ colCount,
                                                uint2* __restrict__ colRecs,
                                                unsigned* __restrict__ ovCount,
                                                uint2* __restrict__ ovRecs) {
  __shared__ unsigned short S[2][64 * 256];   // 2 x 32KB, swizzled tiles
  // grid (16,4,8) = 512 blocks; flatten x-fastest, remap so XCD k
  // (dispatch id % 8) runs exactly batch b=k (64 blocks). 512 % 8 == 0.
  const int hw = blockIdx.x + (blockIdx.y << 4) + (blockIdx.z << 6);
  const int lg = ((hw & 7) << 6) | (hw >> 3);
  const int b = lg >> 6;
  const int t0 = (lg & 15) << 7;          // *128
  const int sr0 = ((lg >> 4) & 3) << 9;   // *512
  const int tid = threadIdx.x;
  const int w = tid >> 6, lane = tid & 63;
  const int half = lane >> 5, ln = lane & 31;

  // A: both 64-row vm halves staged concurrently; wave w reads half (w>>1)
  stage_tile_async(vmb + ((size_t)b * kT + t0) * kD, S[0], w, lane);
  stage_tile_async(vmb + ((size_t)b * kT + t0 + 64) * kD, S[1], w, lane);
  __syncthreads();  // both halves resident
  uint4 afr[16];
  {
    const unsigned short* Sa = S[w >> 1];
#pragma unroll
    for (int kc = 0; kc < 16; ++kc)
      afr[kc] = lds_frag(Sa, (w & 1) * 32 + ln, kc, half);
  }
  __syncthreads();  // afr reads done block-wide before buffers are reused

  // prologue: stage am tile 0
  stage_tile_async(amb + ((size_t)b * kT + sr0) * kD, S[0], w, lane);
  __syncthreads();  // tile 0 resident

  const float* v2p = vn2 + (size_t)b * kT + t0 + w * 32;

  for (int st = 0; st < 8; ++st) {
    const int s0 = sr0 + st * 64;
    const int cur = st & 1;
    if (st < 7)  // prefetch next tile; latency hides under MFMA + epilogue
      stage_tile_async(amb + ((size_t)b * kT + s0 + 64) * kD, S[cur ^ 1], w, lane);
    f32x16 acc[2];
#pragma unroll
    for (int j = 0; j < 2; ++j)
#pragma unroll
      for (int i = 0; i < 16; ++i) acc[j][i] = 0.0f;
#pragma unroll
    for (int kc = 0; kc < 16; ++kc) {
      FragU fa; fa.u4 = afr[kc];
#pragma unroll
      for (int ss = 0; ss < 2; ++ss) {
        FragU fb;
        fb.u4 = lds_frag(S[cur], ss * 32 + ln, kc, half);
        acc[ss] = __builtin_amdgcn_mfma_f32_32x32x16_bf16(fa.v, fb.v, acc[ss], 0, 0, 0);
      }
    }
    // epilogue: col(s)=lane&31, row(t)=(reg&3)+8*(reg>>2)+4*half
    float a2s[2];
#pragma unroll
    for (int ss = 0; ss < 2; ++ss)
      a2s[ss] = an2[(size_t)b * kT + s0 + ss * 32 + ln];
#pragma unroll
    for (int g = 0; g < 4; ++g) {
      const float4 v2 = *reinterpret_cast<const float4*>(v2p + g * 8 + half * 4);
      const float v2a[4] = {v2.x, v2.y, v2.z, v2.w};
#pragma unroll
      for (int ss = 0; ss < 2; ++ss) {
        const int s = s0 + ss * 32 + ln;
        const float a2 = a2s[ss];
        const int c = (b << 11) | s;
#pragma unroll
        for (int q = 0; q < 4; ++q) {
          const float raw = v2a[q] + a2 - 2.0f * acc[ss][4 * g + q];
          if (raw < 7744.0f) {  // == dist < 88; ~3e-4 of entries
            const float dist = sqrtf(fmaxf(raw, 0.0f));
            const float e = expf(-dist);
            if (e >= kMinNormalF) {
              const int t = t0 + w * 32 + g * 8 + half * 4 + q;
              const unsigned slot = atomicAdd(&colCount[c], 1u);
              if (slot < (unsigned)kColCap) {
                colRecs[(size_t)c * kColCap + slot] = make_uint2(__float_as_uint(e), (unsigned)t);
              } else {
                const unsigned pos = ((unsigned)b << 22) | ((unsigned)s << 11) | (unsigned)t;
                const unsigned oi = atomicAdd(ovCount, 1u);
                if (oi < (unsigned)kOvCap) ovRecs[oi] = make_uint2(__float_as_uint(e), pos);
              }
            }
          }
        }
      }
    }
    if (st < 7) __syncthreads();  // next tile resident; S[cur] reads done
  }
}

// ---- Kernel 3: fused finalize + gather + output accumulate (R2-validated) --
// Block u = (bj, ch): 32 threads recompute top-8 for the 32 columns of this
// s-chunk straight from the per-column buckets (mean 0.55 records), pick the
// j-th index, then all 256 threads gather-partial and atomically accumulate
// the pre-scaled partial straight into out (zeroed by prep).
__global__ __launch_bounds__(256) void gather_fused(const float* __restrict__ visual,
                                                    const float* __restrict__ audio,
                                                    const unsigned* __restrict__ colCount,
                                                    const uint2* __restrict__ colRecs,
                                                    const unsigned* __restrict__ ovCount,
                                                    const uint2* __restrict__ ovRecs,
                                                    float* __restrict__ out) {
  __shared__ int sIdx[32];
  const int u = blockIdx.x;              // 4096 = 64 bj x 64 chunks
  const int bj = u >> 6, ch = u & 63;
  const int b = bj >> 3, j = bj & 7;
  const int tid = threadIdx.x;
  if (tid < 32) {
    const int s = ch * 32 + tid;
    const int c = (b << 11) | s;
    unsigned K[8]; int T[8];
#pragma unroll
    for (int i = 0; i < 8; ++i) { K[i] = 0u; T[i] = 0x7FFFFFFF; }
    const int cnt = (int)colCount[c];
    const int m = min(cnt, kColCap);
    for (int i = 0; i < m; ++i) {
      const uint2 r = colRecs[(size_t)c * kColCap + i];
      const unsigned kx = r.x; const int tx = (int)r.y;
      if (kx > K[7] || (kx == K[7] && tx < T[7])) {
        K[7] = kx; T[7] = tx;
#pragma unroll
        for (int q = 7; q >= 1; --q) {
          const bool sw = (K[q] > K[q - 1]) || (K[q] == K[q - 1] && T[q] < T[q - 1]);
          if (sw) {
            const unsigned tk = K[q]; K[q] = K[q - 1]; K[q - 1] = tk;
            const int tt = T[q];      T[q] = T[q - 1]; T[q - 1] = tt;
          }
        }
      }
    }
    if (cnt > kColCap) {  // correctness fallback; normally never taken
      int n = (int)*ovCount;
      if (n > kOvCap) n = kOvCap;
      for (int i = 0; i < n; ++i) {
        const uint2 r = ovRecs[i];
        if ((int)(r.y >> 11) == c) {
          const unsigned kx = r.x; const int tx = (int)(r.y & 2047u);
          if (kx > K[7] || (kx == K[7] && tx < T[7])) {
            K[7] = kx; T[7] = tx;
#pragma unroll
            for (int q = 7; q >= 1; --q) {
              const bool sw = (K[q] > K[q - 1]) || (K[q] == K[q - 1] && T[q] < T[q - 1]);
              if (sw) {
                const unsigned tk = K[q]; K[q] = K[q - 1]; K[q - 1] = tk;
                const int tt = T[q];      T[q] = T[q - 1]; T[q - 1] = tt;
              }
            }
          }
        }
      }
    }
    int mcnt = 0;
#pragma unroll
    for (int i = 0; i < 8; ++i) if (K[i] > 0u) mcnt++;
    int outv[8];
#pragma unroll
    for (int i = 0; i < 8; ++i) outv[i] = T[i];
    int cand = 0;
    for (int r = mcnt; r < 8; ++r) {
      bool taken = true;
      while (taken) {
        taken = false;
#pragma unroll
        for (int q = 0; q < 8; ++q)
          if (q < mcnt && T[q] == cand) taken = true;
        if (taken) cand++;
      }
      outv[r] = cand++;
    }
    sIdx[tid] = outv[j];
  }
  __syncthreads();
  float accV = 0.f, accA = 0.f;
  for (int i = 0; i < 32; ++i) {
    const int t = sIdx[i];
    const size_t base = ((size_t)b * kT + t) * kD + tid;
    accV += visual[base];
    accA += audio[base];
  }
  atomicAdd(&out[(size_t)bj * kD + tid], accV * (1.0f / kT));
  atomicAdd(&out[(size_t)kB * kK * kD + (size_t)bj * kD + tid], accA * (1.0f / kT));
}

extern "C" void kernel_launch(void* const* d_in, const int* in_sizes, int n_in,
                              void* d_out, int out_size, void* d_ws, size_t ws_size,
                              hipStream_t stream) {
  (void)in_sizes; (void)n_in; (void)out_size; (void)ws_size;
  const float* visual = (const float*)d_in[0];
  const float* audio  = (const float*)d_in[1];
  const float* Wv     = (const float*)d_in[2];
  const float* Wa     = (const float*)d_in[3];
  float* out = (float*)d_out;

  // workspace layout (~27 MB). [vn2|an2|colCount|ovCount] contiguous: zeroed by prep.
  char* ws = (char*)d_ws;
  unsigned short* WvT = (unsigned short*)ws;                // kD*kD bf16 128KB
  unsigned short* WaT = WvT + (size_t)kD * kD;
  unsigned short* vmb = WaT + (size_t)kD * kD;              // kM*kD bf16  8MB
  unsigned short* amb = vmb + (size_t)kM * kD;              // 8MB
  float* vn2 = (float*)(amb + (size_t)kM * kD);             // kM f32 (zeroed)
  float* an2 = vn2 + kM;                                    // kM f32 (zeroed)
  unsigned* colCount = (unsigned*)(an2 + kM);               // kNC u32 (zeroed)
  unsigned* ovCount  = colCount + kNC;                      // 1 u32 +7 pad (zeroed)
  uint2* colRecs = (uint2*)(ovCount + 8);                   // kNC*kColCap uint2 8MB
  uint2* ovRecs  = colRecs + (size_t)kNC * kColCap;         // kOvCap uint2 1MB
  const int zeroWords = 2 * kM + kNC + 8;

  prep<<<dim3(160), 256, 0, stream>>>(Wv, Wa, WvT, WaT, (unsigned*)vn2, zeroWords,
                                      (unsigned*)out);
  gemm_hyb<<<dim3(kM / 64, 1, 2), 256, 0, stream>>>(visual, audio, WvT, WaT,
                                                    vmb, amb, vn2, an2);
  keys_v18<<<dim3(kT / 128, kT / 512, kB), 256, 0, stream>>>(vmb, amb, vn2, an2,
                                                             colCount, colRecs, ovCount, ovRecs);
  gather_fused<<<dim3(4096), 256, 0, stream>>>(visual, audio, colCount, colRecs,
                                               ovCount, ovRecs, out);
}